// Round 13
// baseline (171.317 us; speedup 1.0000x reference)
//
#include <hip/hip_runtime.h>
#include <hip/hip_bf16.h>
#include <cstdint>
#include <cstddef>

#define BATCH   2048
#define DIM     1024   // D == H == 1024
#define NSTEPS  2      // RK3 steps; h = 1/NSTEPS

typedef __attribute__((ext_vector_type(8))) short short8;
typedef __attribute__((ext_vector_type(4))) float f32x4;
typedef _Float16 half8 __attribute__((ext_vector_type(8)));

static __device__ __forceinline__ unsigned short f2h(float x) {
    _Float16 h = (_Float16)x;                    // v_cvt_f16_f32 (RTN)
    return __builtin_bit_cast(unsigned short, h);
}
static __device__ __forceinline__ float h2f(unsigned short u) {
    return (float)__builtin_bit_cast(_Float16, u);
}
static __device__ __forceinline__ float tanh_fast(float x) {
    // exact at saturation (e=inf -> 1, e=0 -> -1); rel err ~2e-6
    float e = __expf(2.0f * x);
    return 1.0f - 2.0f / (e + 1.0f);
}

// ---------------------------------------------------------------------------
// Fused prep (ONE dispatch): z/zin init (all 2048 blocks) + W1/W2 transpose
// to f16 [N][K] (blocks 0..511, one 64x64 tile each).
// ---------------------------------------------------------------------------
__global__ __launch_bounds__(256) void prep_all(const float* __restrict__ W1,
                                                const float* __restrict__ W2,
                                                const float* __restrict__ z0,
                                                float* __restrict__ z,
                                                unsigned short* __restrict__ W1T,
                                                unsigned short* __restrict__ W2T,
                                                unsigned short* __restrict__ zin) {
    __shared__ unsigned short tile[64][65];
    const int b = blockIdx.x;

    {   // init: one float4 per thread
        const int i = b * 256 + threadIdx.x;
        float4 v = ((const float4*)z0)[i];
        ((float4*)z)[i] = v;
        ushort4 q;
        q.x = f2h(v.x); q.y = f2h(v.y); q.z = f2h(v.z); q.w = f2h(v.w);
        ((ushort4*)zin)[i] = q;
    }

    if (b < 512) {  // transpose one 64x64 tile of W1 (b<256) or W2
        const float* in = (b < 256) ? W1 : W2;
        unsigned short* out = (b < 256) ? W1T : W2T;
        const int tb = b & 255;
        const int nb = (tb & 15) * 64, kb = (tb >> 4) * 64;
        const int cx = threadIdx.x & 63, ry = threadIdx.x >> 6;
#pragma unroll
        for (int r = 0; r < 16; ++r) {
            int k = r * 4 + ry;
            tile[cx][k] = f2h(in[(size_t)(kb + k) * DIM + (nb + cx)]);
        }
        __syncthreads();
#pragma unroll
        for (int r = 0; r < 16; ++r) {
            int n = r * 4 + ry;
            out[(size_t)(nb + n) * DIM + (kb + cx)] = tile[n][cx];
        }
    }
}

// ---------------------------------------------------------------------------
// GEMM: C[m][n] = sum_k A[m][k] * Bw[n][k]  (+ fused epilogue), f16 inputs.
//
// Tile 64x64, 4 waves, SPLIT-K-4 mod-interleaved: wave w computes the FULL
// 64x64 tile over K-chunks t = w, w+4, w+8, w+12 (4x4 frags of 16x16x32 f16).
// Each A-row / B-col is read from LDS exactly ONCE per K-chunk -> main-loop
// LDS reads halve vs the 2x2-wave full-K layout (R12's binding resource:
// LDS port ~5.1 of 8.7 us body). Grid 512 -> 2 blocks/CU (52 KB LDS).
// Triple-buffered staging, counted vmcnt(4) distance-2 pipeline, fully
// unrolled 16-step K-loop. XCD swizzle.
//
// Reduce: waves 1..3 write 64x68-padded f32 partials to the dead staging LDS
// (stride-68 -> 2-way banks = free); wave 0 sums + writes final; all 256
// threads then run the standard row x 16-col vectorized epilogue. accb f16.
//
// MODE 0: hid = f16(tanh(C+b))
// MODE 1 (k1): accb = f16(k);      zin = f16(z + (h/2) k)
// MODE 2 (k2): a0 = accb;          zin = f16(z + h (2k - a0)); accb = f16(a0 + 4k)
// MODE 3 (k3): z += (h/6)(accb+k); zin = f16(z)
// MODE 4     : like 3 but final step - no zin store
// ---------------------------------------------------------------------------
template<int MODE>
__global__ __launch_bounds__(256, 2) void gemm4k(const unsigned short* __restrict__ A,
                                                 const unsigned short* __restrict__ Bw,
                                                 const float* __restrict__ bias,
                                                 unsigned short* __restrict__ hidOut,
                                                 float* __restrict__ zbuf,
                                                 unsigned short* __restrict__ accb,
                                                 unsigned short* __restrict__ zinOut) {
    constexpr float hstep = 1.0f / NSTEPS;
    __shared__ char smem_raw[53248];             // 52 KB (48 staging ∪ 3x17KB reduce)
    short8* stg = (short8*)smem_raw;             // 3 bufs x 1024 slots (A 512 | B 512)
    float*  red = (float*)smem_raw;              // 3 regions x 4352 f32 (64 x 68)

    const int tid  = threadIdx.x;
    const int wave = tid >> 6;
    const int lane = tid & 63;
    const int l15 = lane & 15, lhi = lane >> 4;

    // XCD swizzle: bid%8 = XCD; XCD owns bm in [xcd*4,+4) x all bn.
    const int bid = blockIdx.x;
    const int xcd = bid & 7, loc = bid >> 3;     // loc 0..63
    const int bm = xcd * 4 + (loc >> 4);         // 0..31
    const int bn = loc & 15;                     // 0..15

    f32x4 acc[4][4] = {};

    // Staging: 4 global_load_lds per thread (2 A + 2 B) cover 1024 slots.
    // LDS slot s (linear dest) holds global (row = s>>3, k16 = (s&7)^(row&7)).
    int offA[2], offB[2];
#pragma unroll
    for (int c = 0; c < 2; ++c) {
        const int s = c * 256 + tid;             // [0,512)
        const int row = s >> 3, k16 = (s & 7) ^ (row & 7);
        offA[c] = (bm * 64 + row) * DIM + k16 * 8;
        offB[c] = (bn * 64 + row) * DIM + k16 * 8;
    }

    auto stage = [&](int sbuf, int t) {
#pragma unroll
        for (int c = 0; c < 2; ++c)
            __builtin_amdgcn_global_load_lds(
                (const __attribute__((address_space(1))) void*)(A + offA[c] + t * 64),
                (__attribute__((address_space(3))) void*)&stg[sbuf * 1024 + c * 256 + tid],
                16, 0, 0);
#pragma unroll
        for (int c = 0; c < 2; ++c)
            __builtin_amdgcn_global_load_lds(
                (const __attribute__((address_space(1))) void*)(Bw + offB[c] + t * 64),
                (__attribute__((address_space(3))) void*)&stg[sbuf * 1024 + 512 + c * 256 + tid],
                16, 0, 0);
    };

    stage(0, 0);
    stage(1, 1);  // 8 loads in flight

#pragma unroll
    for (int t = 0; t < 16; ++t) {
        if (t < 15) asm volatile("s_waitcnt vmcnt(4)" ::: "memory");
        else        asm volatile("s_waitcnt vmcnt(0)" ::: "memory");
        __builtin_amdgcn_s_barrier();          // raw: no vmcnt(0) drain
        __builtin_amdgcn_sched_barrier(0);     // don't hoist stage above barrier

        if (t + 2 < 16) stage((t + 2) % 3, t + 2);

        if ((t & 3) == wave) {                 // this wave owns chunk t
            const char* sa = (const char*)&stg[(t % 3) * 1024];
            const char* sb = sa + 8192;
#pragma unroll
            for (int kk = 0; kk < 2; ++kk) {
                half8 af[4], bq[4];
#pragma unroll
                for (int m = 0; m < 4; ++m) {
                    const int row  = m * 16 + l15;
                    const int byte = row * 128 + ((kk * 64 + lhi * 16) ^ ((row & 7) << 4));
                    af[m] = *(const half8*)(sa + byte);
                }
#pragma unroll
                for (int n = 0; n < 4; ++n) {
                    const int row  = n * 16 + l15;
                    const int byte = row * 128 + ((kk * 64 + lhi * 16) ^ ((row & 7) << 4));
                    bq[n] = *(const half8*)(sb + byte);
                }
                __builtin_amdgcn_s_setprio(1);
#pragma unroll
                for (int m = 0; m < 4; ++m)
#pragma unroll
                    for (int n = 0; n < 4; ++n)
                        acc[m][n] = __builtin_amdgcn_mfma_f32_16x16x32_f16(af[m], bq[n], acc[m][n], 0, 0, 0);
                __builtin_amdgcn_s_setprio(0);
            }
        }
    }

    __syncthreads();  // staging LDS dead; reduce regions take over

    // ---- waves 1..3 write padded 64x68 f32 partials ----
    if (wave != 0) {
        float* reg = red + (wave - 1) * 4352;
#pragma unroll
        for (int m = 0; m < 4; ++m)
#pragma unroll
            for (int n = 0; n < 4; ++n)
#pragma unroll
                for (int r = 0; r < 4; ++r)
                    reg[(m * 16 + lhi * 4 + r) * 68 + n * 16 + l15] = acc[m][n][r];
    }
    __syncthreads();

    // ---- wave 0: sum partials, write final (region 0) ----
    if (wave == 0) {
#pragma unroll
        for (int m = 0; m < 4; ++m)
#pragma unroll
            for (int n = 0; n < 4; ++n)
#pragma unroll
                for (int r = 0; r < 4; ++r) {
                    const int idx = (m * 16 + lhi * 4 + r) * 68 + n * 16 + l15;
                    red[idx] = acc[m][n][r] + red[idx] + red[4352 + idx] + red[8704 + idx];
                }
    }
    __syncthreads();

    // ---- all 256 threads: one row x 16 contiguous cols each ----
    {
        const int row  = tid >> 2;                 // 0..63
        const int c0   = (tid & 3) << 4;           // 0,16,32,48
        const int base = row * 68 + c0;

        f32x4 sum[4];
#pragma unroll
        for (int q = 0; q < 4; ++q)
            sum[q] = *(const f32x4*)(red + base + 4 * q);

        const int grow = bm * 64 + row;
        const int gcol = bn * 64 + c0;
        const size_t gidx = (size_t)grow * DIM + gcol;

        // f16 accb fragment (16 halves) for modes 2/3/4
        unsigned short al[16];
        if (MODE >= 2) {
            short8 a0 = *(const short8*)&accb[gidx];
            short8 a1 = *(const short8*)&accb[gidx + 8];
#pragma unroll
            for (int j = 0; j < 8; ++j) {
                al[j]     = (unsigned short)a0[j];
                al[j + 8] = (unsigned short)a1[j];
            }
        }

        unsigned short hh[16];
        unsigned short na[16];   // new accb (modes 1,2)
#pragma unroll
        for (int q = 0; q < 4; ++q) {
            f32x4 v = sum[q] + *(const f32x4*)&bias[gcol + 4 * q];
            if (MODE == 0) {
#pragma unroll
                for (int j = 0; j < 4; ++j) hh[q * 4 + j] = f2h(tanh_fast(v[j]));
            } else if (MODE == 1) {        // k1
                f32x4 z = *(const f32x4*)&zbuf[gidx + 4 * q];
#pragma unroll
                for (int j = 0; j < 4; ++j) {
                    na[q * 4 + j] = f2h(v[j]);
                    hh[q * 4 + j] = f2h(z[j] + (0.5f * hstep) * v[j]);
                }
            } else if (MODE == 2) {        // k2
                f32x4 z = *(const f32x4*)&zbuf[gidx + 4 * q];
#pragma unroll
                for (int j = 0; j < 4; ++j) {
                    const float k1 = h2f(al[q * 4 + j]);
                    hh[q * 4 + j] = f2h(z[j] + hstep * (2.0f * v[j] - k1));
                    na[q * 4 + j] = f2h(k1 + 4.0f * v[j]);
                }
            } else {                       // MODE 3/4: k3, finalize step
                f32x4 z = *(const f32x4*)&zbuf[gidx + 4 * q];
                f32x4 zn;
#pragma unroll
                for (int j = 0; j < 4; ++j)
                    zn[j] = z[j] + (hstep / 6.0f) * (h2f(al[q * 4 + j]) + v[j]);
                *(f32x4*)&zbuf[gidx + 4 * q] = zn;
                if (MODE == 3) {
#pragma unroll
                    for (int j = 0; j < 4; ++j) hh[q * 4 + j] = f2h(zn[j]);
                }
            }
        }
        if (MODE != 4) {
            short8 s0, s1;
#pragma unroll
            for (int j = 0; j < 8; ++j) { s0[j] = (short)hh[j]; s1[j] = (short)hh[j + 8]; }
            if (MODE == 0) {
                *(short8*)&hidOut[gidx] = s0;  *(short8*)&hidOut[gidx + 8] = s1;
            } else {
                *(short8*)&zinOut[gidx] = s0;  *(short8*)&zinOut[gidx + 8] = s1;
            }
        }
        if (MODE == 1 || MODE == 2) {
            short8 a0, a1;
#pragma unroll
            for (int j = 0; j < 8; ++j) { a0[j] = (short)na[j]; a1[j] = (short)na[j + 8]; }
            *(short8*)&accb[gidx] = a0;  *(short8*)&accb[gidx + 8] = a1;
        }
    }
}

// ---------------------------------------------------------------------------
extern "C" void kernel_launch(void* const* d_in, const int* in_sizes, int n_in,
                              void* d_out, int out_size, void* d_ws, size_t ws_size,
                              hipStream_t stream) {
    (void)in_sizes; (void)n_in; (void)out_size; (void)ws_size;
    const float* z0 = (const float*)d_in[0];
    const float* W1 = (const float*)d_in[1];
    const float* b1 = (const float*)d_in[2];
    const float* W2 = (const float*)d_in[3];
    const float* b2 = (const float*)d_in[4];
    float* zbuf = (float*)d_out;  // fp32 state lives in d_out

    char* ws = (char*)d_ws;
    unsigned short* W1T = (unsigned short*)(ws);                 // 2 MB  f16 [H][D]
    unsigned short* W2T = (unsigned short*)(ws + (2u  << 20));   // 2 MB  f16 [D][H]
    unsigned short* zin = (unsigned short*)(ws + (4u  << 20));   // 4 MB  f16
    unsigned short* hid = (unsigned short*)(ws + (8u  << 20));   // 4 MB  f16
    unsigned short* accb= (unsigned short*)(ws + (12u << 20));   // 4 MB  f16

    prep_all<<<(BATCH * DIM / 4) / 256, 256, 0, stream>>>(W1, W2, z0, zbuf, W1T, W2T, zin);

    for (int s = 0; s < NSTEPS; ++s) {  // Kutta RK3: 3 stages x 2 GEMMs
        gemm4k<0><<<512, 256, 0, stream>>>(zin, W1T, b1, hid, nullptr, nullptr, nullptr);
        gemm4k<1><<<512, 256, 0, stream>>>(hid, W2T, b2, nullptr, zbuf, accb, zin);
        gemm4k<0><<<512, 256, 0, stream>>>(zin, W1T, b1, hid, nullptr, nullptr, nullptr);
        gemm4k<2><<<512, 256, 0, stream>>>(hid, W2T, b2, nullptr, zbuf, accb, zin);
        gemm4k<0><<<512, 256, 0, stream>>>(zin, W1T, b1, hid, nullptr, nullptr, nullptr);
        if (s == NSTEPS - 1)
            gemm4k<4><<<512, 256, 0, stream>>>(hid, W2T, b2, nullptr, zbuf, accb, zin);
        else
            gemm4k<3><<<512, 256, 0, stream>>>(hid, W2T, b2, nullptr, zbuf, accb, zin);
    }
}

// Round 14
// 130.700 us; speedup vs baseline: 1.3108x; 1.3108x over previous
//
#include <hip/hip_runtime.h>
#include <hip/hip_bf16.h>
#include <cstdint>
#include <cstddef>

#define BATCH   2048
#define DIM     1024   // D == H == 1024
#define NSTEPS  2      // RK3 steps; h = 1/NSTEPS

typedef __attribute__((ext_vector_type(8))) short short8;
typedef __attribute__((ext_vector_type(4))) float f32x4;
typedef _Float16 half8 __attribute__((ext_vector_type(8)));

static __device__ __forceinline__ unsigned short f2h(float x) {
    _Float16 h = (_Float16)x;                    // v_cvt_f16_f32 (RTN)
    return __builtin_bit_cast(unsigned short, h);
}
static __device__ __forceinline__ float h2f(unsigned short u) {
    return (float)__builtin_bit_cast(_Float16, u);
}
static __device__ __forceinline__ float tanh_fast(float x) {
    // exact at saturation (e=inf -> 1, e=0 -> -1); rel err ~2e-6
    float e = __expf(2.0f * x);
    return 1.0f - 2.0f / (e + 1.0f);
}

// ---------------------------------------------------------------------------
// Fused prep (ONE dispatch): z/zin init (all 2048 blocks) + W1/W2 transpose
// to f16 [N][K] (blocks 0..511, one 64x64 tile each).
// ---------------------------------------------------------------------------
__global__ __launch_bounds__(256) void prep_all(const float* __restrict__ W1,
                                                const float* __restrict__ W2,
                                                const float* __restrict__ z0,
                                                float* __restrict__ z,
                                                unsigned short* __restrict__ W1T,
                                                unsigned short* __restrict__ W2T,
                                                unsigned short* __restrict__ zin) {
    __shared__ unsigned short tile[64][65];
    const int b = blockIdx.x;

    {   // init: one float4 per thread
        const int i = b * 256 + threadIdx.x;
        float4 v = ((const float4*)z0)[i];
        ((float4*)z)[i] = v;
        ushort4 q;
        q.x = f2h(v.x); q.y = f2h(v.y); q.z = f2h(v.z); q.w = f2h(v.w);
        ((ushort4*)zin)[i] = q;
    }

    if (b < 512) {  // transpose one 64x64 tile of W1 (b<256) or W2
        const float* in = (b < 256) ? W1 : W2;
        unsigned short* out = (b < 256) ? W1T : W2T;
        const int tb = b & 255;
        const int nb = (tb & 15) * 64, kb = (tb >> 4) * 64;
        const int cx = threadIdx.x & 63, ry = threadIdx.x >> 6;
#pragma unroll
        for (int r = 0; r < 16; ++r) {
            int k = r * 4 + ry;
            tile[cx][k] = f2h(in[(size_t)(kb + k) * DIM + (nb + cx)]);
        }
        __syncthreads();
#pragma unroll
        for (int r = 0; r < 16; ++r) {
            int n = r * 4 + ry;
            out[(size_t)(nb + n) * DIM + (kb + cx)] = tile[n][cx];
        }
    }
}

// ---------------------------------------------------------------------------
// GEMM: C[m][n] = sum_k A[m][k] * Bw[n][k]  (+ fused epilogue), f16 inputs.
//
// Tile 64x64, 4 waves, wave (rsub,wc) owns a full-K 32x32 output (2x2 frags
// of mfma_f32_16x16x32_f16). Grid 512 -> 2 blocks/CU (48 KB LDS) for TLP.
// (R13's split-K-4 single-owner variant regressed 131->171: all-waves-active
// duplicated reads overlap latency better than halved single-owner reads.)
// Triple-buffered staging, counted vmcnt(4) distance-2 pipeline, fully
// unrolled 16-step K-loop. Both kk sub-steps' ds_reads batched before one
// 8-MFMA setprio cluster. XCD swizzle: XCD owns bm-band of 4 x all bn.
//
// Epilogue: padded 18 KB exchange (stride 36 f32), then 256 threads own one
// row x 16 contiguous cols; vectorized f32x4/short8 global IO. accb is f16.
//
// MODE 0: hid = f16(tanh(C+b))
// MODE 1 (k1): accb = f16(k);      zin = f16(z + (h/2) k)
// MODE 2 (k2): a0 = accb;          zin = f16(z + h (2k - a0)); accb = f16(a0 + 4k)
// MODE 3 (k3): z += (h/6)(accb+k); zin = f16(z)
// MODE 4     : like 3 but final step - no zin store
// ---------------------------------------------------------------------------
template<int MODE>
__global__ __launch_bounds__(256, 2) void gemm4w(const unsigned short* __restrict__ A,
                                                 const unsigned short* __restrict__ Bw,
                                                 const float* __restrict__ bias,
                                                 unsigned short* __restrict__ hidOut,
                                                 float* __restrict__ zbuf,
                                                 unsigned short* __restrict__ accb,
                                                 unsigned short* __restrict__ zinOut) {
    constexpr float hstep = 1.0f / NSTEPS;
    __shared__ char smem_raw[49152];             // 48 KB (staging ∪ exchange)
    short8* stg = (short8*)smem_raw;             // 3 bufs x 1024 slots (A 512 | B 512)
    float*  xch = (float*)smem_raw;              // 4 regions x 1152 f32 = 18 KB

    const int tid  = threadIdx.x;
    const int wave = tid >> 6;
    const int lane = tid & 63;
    const int l15 = lane & 15, lhi = lane >> 4;
    const int rsub = wave >> 1;        // row half of 64
    const int wc   = wave & 1;         // col half of 64

    // XCD swizzle: bid%8 = XCD; XCD owns bm in [xcd*4,+4) x all bn.
    const int bid = blockIdx.x;
    const int xcd = bid & 7, loc = bid >> 3;     // loc 0..63
    const int bm = xcd * 4 + (loc >> 4);         // 0..31
    const int bn = loc & 15;                     // 0..15

    f32x4 acc[2][2] = {};

    // Staging: 4 global_load_lds per thread (2 A + 2 B) cover 1024 slots.
    // LDS slot s (linear dest) holds global (row = s>>3, k16 = (s&7)^(row&7)).
    int offA[2], offB[2];
#pragma unroll
    for (int c = 0; c < 2; ++c) {
        const int s = c * 256 + tid;             // [0,512)
        const int row = s >> 3, k16 = (s & 7) ^ (row & 7);
        offA[c] = (bm * 64 + row) * DIM + k16 * 8;
        offB[c] = (bn * 64 + row) * DIM + k16 * 8;
    }

    auto stage = [&](int sbuf, int t) {
#pragma unroll
        for (int c = 0; c < 2; ++c)
            __builtin_amdgcn_global_load_lds(
                (const __attribute__((address_space(1))) void*)(A + offA[c] + t * 64),
                (__attribute__((address_space(3))) void*)&stg[sbuf * 1024 + c * 256 + tid],
                16, 0, 0);
#pragma unroll
        for (int c = 0; c < 2; ++c)
            __builtin_amdgcn_global_load_lds(
                (const __attribute__((address_space(1))) void*)(Bw + offB[c] + t * 64),
                (__attribute__((address_space(3))) void*)&stg[sbuf * 1024 + 512 + c * 256 + tid],
                16, 0, 0);
    };

    stage(0, 0);
    stage(1, 1);  // 8 loads in flight

    // Pre-computed per-lane swizzled LDS byte offsets (row-invariant parts).
    const int arow0 = rsub * 32 + l15;           // +16 for m=1
    const int brow0 = wc   * 32 + l15;           // +16 for n=1

#pragma unroll
    for (int t = 0; t < 16; ++t) {
        if (t < 15) asm volatile("s_waitcnt vmcnt(4)" ::: "memory");
        else        asm volatile("s_waitcnt vmcnt(0)" ::: "memory");
        __builtin_amdgcn_s_barrier();          // raw: no vmcnt(0) drain
        __builtin_amdgcn_sched_barrier(0);     // don't hoist stage above barrier

        if (t + 2 < 16) stage((t + 2) % 3, t + 2);

        const char* sa = (const char*)&stg[(t % 3) * 1024];
        const char* sb = sa + 8192;
        half8 af[2][2], bq[2][2];
#pragma unroll
        for (int kk = 0; kk < 2; ++kk) {
#pragma unroll
            for (int m = 0; m < 2; ++m) {
                const int row  = arow0 + m * 16;
                const int byte = row * 128 + ((kk * 64 + lhi * 16) ^ ((row & 7) << 4));
                af[kk][m] = *(const half8*)(sa + byte);
            }
#pragma unroll
            for (int n = 0; n < 2; ++n) {
                const int row  = brow0 + n * 16;
                const int byte = row * 128 + ((kk * 64 + lhi * 16) ^ ((row & 7) << 4));
                bq[kk][n] = *(const half8*)(sb + byte);
            }
        }
        __builtin_amdgcn_s_setprio(1);
#pragma unroll
        for (int kk = 0; kk < 2; ++kk)
#pragma unroll
            for (int m = 0; m < 2; ++m)
#pragma unroll
                for (int n = 0; n < 2; ++n)
                    acc[m][n] = __builtin_amdgcn_mfma_f32_16x16x32_f16(af[kk][m], bq[kk][n], acc[m][n], 0, 0, 0);
        __builtin_amdgcn_s_setprio(0);
    }

    __syncthreads();  // staging LDS quiesced before exchange overwrites it

    // ---- waves write full-K 32x32 tiles to the padded exchange ----
    {
        const int rbase = (rsub * 2 + wc) * 1152;   // region: 32 rows x 36 f32
#pragma unroll
        for (int m = 0; m < 2; ++m)
#pragma unroll
            for (int n = 0; n < 2; ++n)
#pragma unroll
                for (int r = 0; r < 4; ++r)
                    xch[rbase + (m * 16 + lhi * 4 + r) * 36 + n * 16 + l15] = acc[m][n][r];
    }
    __syncthreads();

    // ---- all 256 threads: one row x 16 contiguous cols each ----
    {
        const int row  = tid >> 2;                 // 0..63
        const int c0   = (tid & 3) << 4;           // 0,16,32,48
        const int reg  = ((row >> 5) << 1) + (c0 >> 5);
        const int base = reg * 1152 + (row & 31) * 36 + (c0 & 31);

        f32x4 sum[4];
#pragma unroll
        for (int q = 0; q < 4; ++q)
            sum[q] = *(const f32x4*)(xch + base + 4 * q);

        const int grow = bm * 64 + row;
        const int gcol = bn * 64 + c0;
        const size_t gidx = (size_t)grow * DIM + gcol;

        // f16 accb fragment (16 halves) for modes 2/3/4
        unsigned short al[16];
        if (MODE >= 2) {
            short8 a0 = *(const short8*)&accb[gidx];
            short8 a1 = *(const short8*)&accb[gidx + 8];
#pragma unroll
            for (int j = 0; j < 8; ++j) {
                al[j]     = (unsigned short)a0[j];
                al[j + 8] = (unsigned short)a1[j];
            }
        }

        unsigned short hh[16];
        unsigned short na[16];   // new accb (modes 1,2)
#pragma unroll
        for (int q = 0; q < 4; ++q) {
            f32x4 v = sum[q] + *(const f32x4*)&bias[gcol + 4 * q];
            if (MODE == 0) {
#pragma unroll
                for (int j = 0; j < 4; ++j) hh[q * 4 + j] = f2h(tanh_fast(v[j]));
            } else if (MODE == 1) {        // k1
                f32x4 z = *(const f32x4*)&zbuf[gidx + 4 * q];
#pragma unroll
                for (int j = 0; j < 4; ++j) {
                    na[q * 4 + j] = f2h(v[j]);
                    hh[q * 4 + j] = f2h(z[j] + (0.5f * hstep) * v[j]);
                }
            } else if (MODE == 2) {        // k2
                f32x4 z = *(const f32x4*)&zbuf[gidx + 4 * q];
#pragma unroll
                for (int j = 0; j < 4; ++j) {
                    const float k1 = h2f(al[q * 4 + j]);
                    hh[q * 4 + j] = f2h(z[j] + hstep * (2.0f * v[j] - k1));
                    na[q * 4 + j] = f2h(k1 + 4.0f * v[j]);
                }
            } else {                       // MODE 3/4: k3, finalize step
                f32x4 z = *(const f32x4*)&zbuf[gidx + 4 * q];
                f32x4 zn;
#pragma unroll
                for (int j = 0; j < 4; ++j)
                    zn[j] = z[j] + (hstep / 6.0f) * (h2f(al[q * 4 + j]) + v[j]);
                *(f32x4*)&zbuf[gidx + 4 * q] = zn;
                if (MODE == 3) {
#pragma unroll
                    for (int j = 0; j < 4; ++j) hh[q * 4 + j] = f2h(zn[j]);
                }
            }
        }
        if (MODE != 4) {
            short8 s0, s1;
#pragma unroll
            for (int j = 0; j < 8; ++j) { s0[j] = (short)hh[j]; s1[j] = (short)hh[j + 8]; }
            if (MODE == 0) {
                *(short8*)&hidOut[gidx] = s0;  *(short8*)&hidOut[gidx + 8] = s1;
            } else {
                *(short8*)&zinOut[gidx] = s0;  *(short8*)&zinOut[gidx + 8] = s1;
            }
        }
        if (MODE == 1 || MODE == 2) {
            short8 a0, a1;
#pragma unroll
            for (int j = 0; j < 8; ++j) { a0[j] = (short)na[j]; a1[j] = (short)na[j + 8]; }
            *(short8*)&accb[gidx] = a0;  *(short8*)&accb[gidx + 8] = a1;
        }
    }
}

// ---------------------------------------------------------------------------
extern "C" void kernel_launch(void* const* d_in, const int* in_sizes, int n_in,
                              void* d_out, int out_size, void* d_ws, size_t ws_size,
                              hipStream_t stream) {
    (void)in_sizes; (void)n_in; (void)out_size; (void)ws_size;
    const float* z0 = (const float*)d_in[0];
    const float* W1 = (const float*)d_in[1];
    const float* b1 = (const float*)d_in[2];
    const float* W2 = (const float*)d_in[3];
    const float* b2 = (const float*)d_in[4];
    float* zbuf = (float*)d_out;  // fp32 state lives in d_out

    char* ws = (char*)d_ws;
    unsigned short* W1T = (unsigned short*)(ws);                 // 2 MB  f16 [H][D]
    unsigned short* W2T = (unsigned short*)(ws + (2u  << 20));   // 2 MB  f16 [D][H]
    unsigned short* zin = (unsigned short*)(ws + (4u  << 20));   // 4 MB  f16
    unsigned short* hid = (unsigned short*)(ws + (8u  << 20));   // 4 MB  f16
    unsigned short* accb= (unsigned short*)(ws + (12u << 20));   // 4 MB  f16

    prep_all<<<(BATCH * DIM / 4) / 256, 256, 0, stream>>>(W1, W2, z0, zbuf, W1T, W2T, zin);

    for (int s = 0; s < NSTEPS; ++s) {  // Kutta RK3: 3 stages x 2 GEMMs
        gemm4w<0><<<512, 256, 0, stream>>>(zin, W1T, b1, hid, nullptr, nullptr, nullptr);
        gemm4w<1><<<512, 256, 0, stream>>>(hid, W2T, b2, nullptr, zbuf, accb, zin);
        gemm4w<0><<<512, 256, 0, stream>>>(zin, W1T, b1, hid, nullptr, nullptr, nullptr);
        gemm4w<2><<<512, 256, 0, stream>>>(hid, W2T, b2, nullptr, zbuf, accb, zin);
        gemm4w<0><<<512, 256, 0, stream>>>(zin, W1T, b1, hid, nullptr, nullptr, nullptr);
        if (s == NSTEPS - 1)
            gemm4w<4><<<512, 256, 0, stream>>>(hid, W2T, b2, nullptr, zbuf, accb, zin);
        else
            gemm4w<3><<<512, 256, 0, stream>>>(hid, W2T, b2, nullptr, zbuf, accb, zin);
    }
}